// Round 18
// baseline (7326.527 us; speedup 1.0000x reference)
//
#include <hip/hip_runtime.h>
#include <stdint.h>

// ---------------------------------------------------------------------------
// 3-layer LSTM (B=256,S=512,H=512) + FC(96) -> FLOAT32 out. ROUND-18.
// Base: r17 (PASSED 7145us). Structural change: phase-B L1/L2 run
// CONCURRENTLY on disjoint block sets (software pipeline, lag 1).
//  * 4 batch groups x 64 rows; role A (grp=g, XCD g) = L1, role B (grp=g+4,
//    XCD g+4) = L2. W1/W2 LDS-resident for the whole phase (no restaging).
//  * Phase A: 8 XCD-local 32-block sub-groups run L0 on 32-row tiles
//    (today's structure, batch base remapped). Boundary: full device fence.
//  * Forward h1 stream: dual-write -- plain to local ring (own recurrence)
//    + sc1 stores to LLC ring (cross-XCD, no wbl2; sc1 visibility proven by
//    r2/r11 cross-XCD flags). Role B reads ring via sc1 loads (proven fresh),
//    8 loads + waitcnt per asm block (no dangling in-flight asm regs).
//  * Flow control: prod/cons AGENT counters with >=1-interval slack; capped
//    polls -> 3e9 sentinel. Non-round-robin placement -> proven slow path.
// Intervals: 1536 -> 1025. Sentinels: <5e8 ws-MB*1e6 | 2e12 launch | 3e9 cap.
// ---------------------------------------------------------------------------

#define HD 512
#define SEQ 512
#define NTHREADS 512
#define KPAD 1032
#define RSL 20
#define GROWA 132
#define GROWB 68
#define TILE64 ((size_t)64 * HD)

typedef _Float16 f16x8 __attribute__((ext_vector_type(8)));
typedef float f32x4 __attribute__((ext_vector_type(4)));

constexpr size_t BARA_OFF = 0;
constexpr size_t XCD_OFF  = 2048;
constexpr size_t BARB_OFF = 4096;
constexpr size_t G8_OFF   = 6144;
constexpr size_t PROD_OFF = 6400;
constexpr size_t CONS_OFF = 6464;
constexpr size_t W0_OFF   = (size_t)1 << 16;
constexpr size_t W0_SZ    = (size_t)32 * 64 * 512 * 2;           // 2MB
constexpr size_t W1_OFF   = W0_OFF + W0_SZ;
constexpr size_t W1_SZ    = (size_t)32 * 64 * 1024 * 2;          // 4MB
constexpr size_t W2_OFF   = W1_OFF + W1_SZ;
constexpr size_t C0_OFF   = W2_OFF + W1_SZ;
constexpr size_t C0_SZ    = (size_t)4 * 64 * HD * 4;             // 512KB
constexpr size_t H2L_OFF  = C0_OFF + C0_SZ;
constexpr size_t H2L_SZ   = (size_t)2 * 4 * TILE64 * 2;          // 512KB
constexpr size_t RL_OFF   = H2L_OFF + H2L_SZ;
constexpr size_t RING_SZ  = (size_t)RSL * 4 * TILE64 * 2;        // 5MB
constexpr size_t RX_OFF   = RL_OFF + RING_SZ;
constexpr size_t SEQ0_OFF = RX_OFF + RING_SZ;
constexpr size_t SEQ0_SZ  = (size_t)4 * SEQ * TILE64 * 2;        // 128MB
constexpr size_t WS_NEED  = SEQ0_OFF + SEQ0_SZ;                  // ~149MB

__device__ inline float sigm(float v) { return 1.f / (1.f + __expf(-v)); }
__device__ inline float tanhf_(float v) {
  float av = fabsf(v);
  float e = __expf(-2.f * av);
  float t = (1.f - e) / (1.f + e);
  return copysignf(t, v);
}

// ---- weight pre-conversion (verified; layout keyed by cg, unchanged) -------
template <int K>
__global__ void convw(const float* __restrict__ whh, const float* __restrict__ wih,
                      _Float16* __restrict__ dst) {
  const int i = blockIdx.x * blockDim.x + threadIdx.x;
  constexpr int TOT = 32 * 64 * K / 4;
  if (i >= TOT) return;
  const int kq = i % (K / 4);
  const int rr = i / (K / 4);
  const int cg = rr >> 6, r = rr & 63;
  const int grow = (r >> 4) * 512 + cg * 16 + (r & 15);
  const int k = kq * 4;
  const float* src = (k < 512) ? (whh + (size_t)grow * 512 + k)
                               : (wih + (size_t)grow * 512 + (k - 512));
  float4 v = *(const float4*)src;
  _Float16 o[4] = {(_Float16)v.x, (_Float16)v.y, (_Float16)v.z, (_Float16)v.w};
  *(uint64_t*)(dst + (size_t)i * 4) = *(const uint64_t*)o;
}

template <int K>
__device__ inline void stage_w(const _Float16* __restrict__ src,
                               _Float16* __restrict__ wlds, int tid) {
  constexpr int C = 64 * K / 8;
#pragma unroll 4
  for (int ci = tid; ci < C; ci += NTHREADS) {
    const int r = ci / (K / 8);
    const int kc = (ci % (K / 8)) * 8;
    *(f16x8*)(wlds + (size_t)r * KPAD + kc) = *(const f16x8*)(src + (size_t)r * K + kc);
  }
}

// ---- phase-A GEMM (verified r12): one B-slice, two A row-tiles -------------
template <int NS>
__device__ inline void do_gemm2(const _Float16* __restrict__ bbase,
                                const _Float16* __restrict__ wlds,
                                int aKoff, int bKoff, int lane, int gp, int nt,
                                f32x4& acc0, f32x4& acc1) {
  const int bcol = nt * 16 + (lane & 15);
  const int krow = (lane >> 4) * 8;
  const _Float16* arow0 = wlds + (size_t)(gp * 32 + (lane & 15)) * KPAD + aKoff + krow;
  const _Float16* arow1 = arow0 + (size_t)16 * KPAD;
  const _Float16* brow  = bbase + (size_t)bcol * HD + bKoff + krow;
  constexpr int CH = (NS > 8) ? 8 : NS;
#pragma unroll
  for (int base = 0; base < NS; base += CH) {
    f16x8 br[CH];
#pragma unroll
    for (int s = 0; s < CH; ++s) br[s] = *(const f16x8*)(brow + (base + s) * 32);
#pragma unroll
    for (int s = 0; s < CH; ++s) {
      f16x8 a0 = *(const f16x8*)(arow0 + (base + s) * 32);
      acc0 = __builtin_amdgcn_mfma_f32_16x16x32_f16(a0, br[s], acc0, 0, 0, 0);
      f16x8 a1 = *(const f16x8*)(arow1 + (base + s) * 32);
      acc1 = __builtin_amdgcn_mfma_f32_16x16x32_f16(a1, br[s], acc1, 0, 0, 0);
    }
  }
}

// ---- 8 sc1 loads + waitcnt in ONE asm block (no dangling in-flight regs) ---
__device__ inline void ldg8_sc1(const _Float16* b, f16x8* br) {
  const _Float16 *p0 = b, *p1 = b + 32, *p2 = b + 64, *p3 = b + 96,
                 *p4 = b + 128, *p5 = b + 160, *p6 = b + 192, *p7 = b + 224;
  asm volatile(
      "global_load_dwordx4 %0, %8, off sc1\n\t"
      "global_load_dwordx4 %1, %9, off sc1\n\t"
      "global_load_dwordx4 %2, %10, off sc1\n\t"
      "global_load_dwordx4 %3, %11, off sc1\n\t"
      "global_load_dwordx4 %4, %12, off sc1\n\t"
      "global_load_dwordx4 %5, %13, off sc1\n\t"
      "global_load_dwordx4 %6, %14, off sc1\n\t"
      "global_load_dwordx4 %7, %15, off sc1\n\t"
      "s_waitcnt vmcnt(0)"
      : "=&v"(br[0]), "=&v"(br[1]), "=&v"(br[2]), "=&v"(br[3]),
        "=&v"(br[4]), "=&v"(br[5]), "=&v"(br[6]), "=&v"(br[7])
      : "v"(p0), "v"(p1), "v"(p2), "v"(p3), "v"(p4), "v"(p5), "v"(p6), "v"(p7)
      : "memory");
}

__device__ inline void stg_sc1(_Float16* p, _Float16 v) {
  unsigned hv = (unsigned)*(const unsigned short*)&v;
  asm volatile("global_store_short %0, %1, off sc1" :: "v"(p), "v"(hv) : "memory");
}

// ---- phase-B GEMM: K=1024 = rec(512, plain) ++ in(512, plain or sc1) -------
template <bool XIN>
__device__ inline void do_gemm_cat(const _Float16* __restrict__ bRec,
                                   const _Float16* __restrict__ bIn,
                                   const _Float16* __restrict__ wlds,
                                   int lane, int gp, int nt,
                                   f32x4& acc0, f32x4& acc1) {
  const int bcol = nt * 16 + (lane & 15);
  const int krow = (lane >> 4) * 8;
  const _Float16* arow0 = wlds + (size_t)(gp * 32 + (lane & 15)) * KPAD + krow;
  const _Float16* arow1 = arow0 + (size_t)16 * KPAD;
  // part 1: recurrent (Whh cols 0..511)
  {
    const _Float16* brow = bRec + (size_t)bcol * HD + krow;
#pragma unroll
    for (int base = 0; base < 16; base += 8) {
      f16x8 br[8];
#pragma unroll
      for (int s = 0; s < 8; ++s) br[s] = *(const f16x8*)(brow + (base + s) * 32);
#pragma unroll
      for (int s = 0; s < 8; ++s) {
        f16x8 a0 = *(const f16x8*)(arow0 + (base + s) * 32);
        acc0 = __builtin_amdgcn_mfma_f32_16x16x32_f16(a0, br[s], acc0, 0, 0, 0);
        f16x8 a1 = *(const f16x8*)(arow1 + (base + s) * 32);
        acc1 = __builtin_amdgcn_mfma_f32_16x16x32_f16(a1, br[s], acc1, 0, 0, 0);
      }
    }
  }
  // part 2: input (Wih cols 512..1023)
  {
    const _Float16* brow = bIn + (size_t)bcol * HD + krow;
    const _Float16* a0b = arow0 + 512;
    const _Float16* a1b = arow1 + 512;
#pragma unroll
    for (int base = 0; base < 16; base += 8) {
      f16x8 br[8];
      if (XIN) {
        ldg8_sc1(brow + base * 32, br);
      } else {
#pragma unroll
        for (int s = 0; s < 8; ++s) br[s] = *(const f16x8*)(brow + (base + s) * 32);
      }
#pragma unroll
      for (int s = 0; s < 8; ++s) {
        f16x8 a0 = *(const f16x8*)(a0b + (base + s) * 32);
        acc0 = __builtin_amdgcn_mfma_f32_16x16x32_f16(a0, br[s], acc0, 0, 0, 0);
        f16x8 a1 = *(const f16x8*)(a1b + (base + s) * 32);
        acc1 = __builtin_amdgcn_mfma_f32_16x16x32_f16(a1, br[s], acc1, 0, 0, 0);
      }
    }
  }
}

// ---- full-fence group barrier (proven r2/3/13) ------------------------------
__device__ inline void group_barrier(unsigned* slots, int cg, unsigned target,
                                     int lane, int wave, bool& dead) {
  __syncthreads();
  if (wave == 0) {
    if (lane == 0) {
      __builtin_amdgcn_fence(__ATOMIC_RELEASE, "agent");
      __hip_atomic_store(&slots[cg], target, __ATOMIC_RELAXED, __HIP_MEMORY_SCOPE_AGENT);
    }
    if (!dead) {
      unsigned* myslot = &slots[lane & 31];
      int spins = 0;
      while (true) {
        unsigned v = __hip_atomic_load(myslot, __ATOMIC_RELAXED, __HIP_MEMORY_SCOPE_AGENT);
        if (__all((int)(v >= target))) break;
        __builtin_amdgcn_s_sleep(1);
        if (++spins > (1 << 22)) { dead = true; break; }
      }
    }
    if (lane == 0) __builtin_amdgcn_fence(__ATOMIC_ACQUIRE, "agent");
  }
  __syncthreads();
}

__global__ __launch_bounds__(NTHREADS, 1) void lstm3_kernel(
    const float* __restrict__ x,
    const float* __restrict__ wih0,
    const float* __restrict__ bih0, const float* __restrict__ bhh0,
    const float* __restrict__ bih1, const float* __restrict__ bhh1,
    const float* __restrict__ bih2, const float* __restrict__ bhh2,
    const float* __restrict__ wfc, const float* __restrict__ bfc,
    float* __restrict__ out, char* __restrict__ ws) {
  __shared__ __align__(16) char smem[150016];
  __shared__ unsigned door, door2;
  __shared__ int deadsh;
  _Float16* wlds = (_Float16*)smem;                 // [64][KPAD]
  float* biasLds = (float*)(smem + 132096);         // [64]
  float* w0Lds   = (float*)(smem + 132352);         // [64]
  float* gmat    = (float*)(smem + 132608);         // A:[32][132] / B:[64][68]
  float* gmatF   = (float*)(smem + 132608);

  const int bid = blockIdx.x;
  const int grp = bid & 7;        // role-group == intended XCD
  const int cg  = bid >> 3;       // column block 0..31 (16 cols)
  const int g   = grp & 3;        // batch group (64 rows)
  const int role = grp >> 2;      // 0 = batch-lo / L1 ; 1 = batch-hi / L2
  const int tid = threadIdx.x;
  const int lane = tid & 63;
  const int wave = tid >> 6;
  // phase-A wave decode (r12): gpA in {0,1} gate-pair, ntA batch-half, kh K-half
  const int gpA = wave & 1, ntA = (wave >> 1) & 1, kh = wave >> 2;
  // phase-B wave decode: gpB row-half (32 A-rows), ntB batch-quarter (16)
  const int gpB = wave >> 2, ntB = wave & 3;
  const int nbase = cg * 16;
  const int ab = tid >> 4;        // phase-A cell batch 0..31
  const int an = tid & 15;        // phase-A cell col 0..15
  const int eb = tid >> 3;        // phase-B cell batch 0..63
  const int ec = tid & 7;         // phase-B cell col 0..7 (cells ec, ec+8)

  unsigned* barA = (unsigned*)(ws + BARA_OFF) + grp * 64;
  unsigned* barB = (unsigned*)(ws + BARB_OFF) + grp * 64;
  unsigned* g8   = (unsigned*)(ws + G8_OFF);
  unsigned* prod = (unsigned*)(ws + PROD_OFF);
  unsigned* cons = (unsigned*)(ws + CONS_OFF);
  const _Float16* wcv0 = (const _Float16*)(ws + W0_OFF) + (size_t)cg * 64 * 512;
  const _Float16* wcv1 = (const _Float16*)(ws + W1_OFF) + (size_t)cg * 64 * 1024;
  const _Float16* wcv2 = (const _Float16*)(ws + W2_OFF) + (size_t)cg * 64 * 1024;
  float*    c0buf = (float*)(ws + C0_OFF);
  _Float16* h2l   = (_Float16*)(ws + H2L_OFF);
  _Float16* ringL = (_Float16*)(ws + RL_OFF);
  _Float16* ringX = (_Float16*)(ws + RX_OFF);
  _Float16* seq0  = (_Float16*)(ws + SEQ0_OFF);

  unsigned barIdxA = 0, fullIdx = 0;
  bool dead = false;
  if (tid == 0) { door = 0; door2 = 0; deadsh = 0; }

  // ---- startup: XCD detect ---------------------------------------------------
  int myxcc = 0;
  asm volatile("s_getreg_b32 %0, hwreg(HW_REG_XCC_ID)" : "=s"(myxcc));
  int* xcds = (int*)(ws + XCD_OFF);
  if (tid == 0) xcds[bid] = myxcc;
  group_barrier(barA, cg, ++barIdxA, lane, wave, dead);
  bool local = true, allsame = true;
  for (int j = 0; j < 32; ++j) local = local && (xcds[grp + 8 * j] == myxcc);
  for (int j = 0; j < 256; ++j) allsame = allsame && (xcds[j] == myxcc);
  if (allsame) local = false;
  const bool fastok = local;

  auto seqT = [&](int t) { return seq0 + ((size_t)(g * SEQ + t)) * TILE64; };
  auto rlT  = [&](int t) { return ringL + ((size_t)((t % RSL) * 4 + g)) * TILE64; };
  auto rxT  = [&](int t) { return ringX + ((size_t)((t % RSL) * 4 + g)) * TILE64; };
  auto h2T  = [&](int s) { return h2l + ((size_t)(s * 4 + g)) * TILE64; };

  // fast-path detect by wave0 (r17 mechanics); optional flag publish
  auto detect0 = [&](unsigned tgt, unsigned* flagp, unsigned flagv) {
    if (lane == 0) {
      *(volatile unsigned*)&barB[cg] = tgt;
      __hip_atomic_store(&barA[cg], tgt, __ATOMIC_RELAXED, __HIP_MEMORY_SCOPE_AGENT);
    }
    if (!dead) {
      bool ok = false;
      const volatile unsigned* fs = &barB[lane & 31];
      for (int it = 0; it < 64 && !ok; ++it) {
        asm volatile("buffer_inv\ns_waitcnt vmcnt(0)" ::: "memory");
        unsigned v = *fs;
        ok = __all((int)(v >= tgt));
      }
      if (!ok) {
        unsigned* ss = &barA[lane & 31];
        int s2 = 0;
        while (true) {
          unsigned v = __hip_atomic_load(ss, __ATOMIC_RELAXED, __HIP_MEMORY_SCOPE_AGENT);
          if (__all((int)(v >= tgt))) break;
          __builtin_amdgcn_s_sleep(1);
          if (++s2 > (1 << 22)) { dead = true; deadsh = 1; break; }
        }
        asm volatile("buffer_inv\ns_waitcnt vmcnt(0)" ::: "memory");
      }
    }
    if (lane == 0) {
      if (flagp) __hip_atomic_store(flagp, flagv, __ATOMIC_RELAXED, __HIP_MEMORY_SCOPE_AGENT);
      __hip_atomic_store(&door, tgt, __ATOMIC_RELEASE, __HIP_MEMORY_SCOPE_WORKGROUP);
    }
  };
  // wave1: wait external flag (AGENT) then ring door2
  auto flagwait1 = [&](unsigned* p, unsigned need, unsigned tgt) {
    if (lane == 0) {
      if (need > 0) {
        int spins = 0;
        while (__hip_atomic_load(p, __ATOMIC_RELAXED, __HIP_MEMORY_SCOPE_AGENT) < need) {
          __builtin_amdgcn_s_sleep(1);
          if (++spins > (1 << 22)) { deadsh = 1; break; }
        }
      }
      __hip_atomic_store(&door2, tgt, __ATOMIC_RELEASE, __HIP_MEMORY_SCOPE_WORKGROUP);
    }
  };
  auto dwait = [&](unsigned tgt) {
    while (__hip_atomic_load(&door, __ATOMIC_ACQUIRE, __HIP_MEMORY_SCOPE_WORKGROUP) < tgt) {}
  };
  auto d2wait = [&](unsigned tgt) {
    while (__hip_atomic_load(&door2, __ATOMIC_ACQUIRE, __HIP_MEMORY_SCOPE_WORKGROUP) < tgt) {}
  };
  auto full_barrier = [&]() {
    group_barrier(barA, cg, ++barIdxA, lane, wave, dead);
    ++fullIdx;
    if (wave == 0) {
      if (cg == 0 && lane == 0)
        __hip_atomic_store(&g8[grp], fullIdx, __ATOMIC_RELAXED, __HIP_MEMORY_SCOPE_AGENT);
      if (!dead) {
        int spins = 0;
        while (true) {
          unsigned vv = (lane < 8)
              ? __hip_atomic_load(&g8[lane], __ATOMIC_RELAXED, __HIP_MEMORY_SCOPE_AGENT)
              : fullIdx;
          if (__all((int)(vv >= fullIdx))) break;
          __builtin_amdgcn_s_sleep(1);
          if (++spins > (1 << 22)) { dead = true; deadsh = 1; break; }
        }
      }
      if (lane == 0) __builtin_amdgcn_fence(__ATOMIC_ACQUIRE, "agent");
    }
    __syncthreads();
  };

  // ================= phase A: layer 0 on 32-row tile ========================
  stage_w<512>(wcv0, wlds, tid);
  if (tid < 64) {
    const int grow2 = (tid >> 4) * 512 + nbase + (tid & 15);
    biasLds[tid] = bih0[grow2] + bhh0[grow2];
    w0Lds[tid] = wih0[grow2];
  }
  __syncthreads();

  const size_t roleoff = (size_t)role * 32 * HD;   // row half within 64-tile
  const int abase = g * 64 + role * 32;            // absolute batch base
  float c0 = 0.f;
  for (int t = 0; t < SEQ; ++t) {
    const unsigned tgt = ++barIdxA;
    if (fastok) {
      if (wave == 0) detect0(tgt, nullptr, 0);
      else dwait(tgt);
    }
    const _Float16* recB = seqT(t ? t - 1 : 0) + roleoff;
    const float xv = x[(size_t)(abase + ab) * SEQ + t];
    f32x4 acc0 = {0.f, 0.f, 0.f, 0.f};
    f32x4 acc1 = {0.f, 0.f, 0.f, 0.f};
    if (t > 0)
      do_gemm2<8>(recB, wlds, kh * 256, kh * 256, lane, gpA, ntA, acc0, acc1);
    {
      const int r0 = (lane >> 4) * 4;
      const int colb = ntA * 16 + (lane & 15);
      const int rb0 = kh * 64 + gpA * 32;
      *(f32x4*)(gmat + (size_t)colb * GROWA + rb0 + r0)      = acc0;
      *(f32x4*)(gmat + (size_t)colb * GROWA + rb0 + 16 + r0) = acc1;
    }
    __syncthreads();
    float pre[4];
#pragma unroll
    for (int q = 0; q < 4; ++q) {
      float s = gmat[(size_t)ab * GROWA + q * 16 + an] +
                gmat[(size_t)ab * GROWA + 64 + q * 16 + an];
      pre[q] = s + biasLds[q * 16 + an] + xv * w0Lds[q * 16 + an];
    }
    const float gi = sigm(pre[0]);
    const float gf = sigm(pre[1]);
    const float gg = tanhf_(pre[2]);
    const float go = sigm(pre[3]);
    c0 = gf * c0 + gi * gg;
    const float h = go * tanhf_(c0);
    (seqT(t) + roleoff)[(size_t)ab * HD + nbase + an] = (_Float16)h;
    if (t == SEQ - 1)
      c0buf[(size_t)(abase + ab) * HD + nbase + an] = c0;
    if (fastok) __syncthreads();
    else group_barrier(barA, cg, tgt, lane, wave, dead);
  }

  // ================= phase boundary: device-wide publish ====================
  full_barrier();

  // ================= phase B: pipelined L1 (role 0) / L2 (role 1) ===========
  stage_w<1024>(role ? wcv2 : wcv1, wlds, tid);
  if (tid < 64) {
    const int grow2 = (tid >> 4) * 512 + nbase + (tid & 15);
    biasLds[tid] = role ? (bih2[grow2] + bhh2[grow2]) : (bih1[grow2] + bhh1[grow2]);
  }
  __syncthreads();

  // per-thread cell states: cells (eb, ec) and (eb, ec+8)
  float cst0 = c0buf[(size_t)(g * 64 + eb) * HD + nbase + ec];
  float cst1 = c0buf[(size_t)(g * 64 + eb) * HD + nbase + ec + 8];
  const _Float16* h0fin = seqT(SEQ - 1);   // full 64-row tile

  for (int t = 0; t < SEQ; ++t) {
    const unsigned tgt = ++barIdxA;
    if (fastok) { if (wave == 0) detect0(tgt, role ? &cons[g] : &prod[g], (unsigned)t); }
    if (wave == 1) {
      const unsigned need = role ? (unsigned)(t + 1)
                                 : ((t >= RSL) ? (unsigned)(t - RSL + 1) : 0u);
      flagwait1(role ? &prod[g] : &cons[g], need, tgt);
    }
    if (fastok && wave != 0) dwait(tgt);
    if (wave != 1) d2wait(tgt);

    f32x4 acc0 = {0.f, 0.f, 0.f, 0.f};
    f32x4 acc1 = {0.f, 0.f, 0.f, 0.f};
    if (!role) {       // L1: rec = h1(t-1) local ring; in = h0 seq tile
      const _Float16* rec = t ? rlT(t - 1) : h0fin;
      do_gemm_cat<false>(rec, seqT(t), wlds, lane, gpB, ntB, acc0, acc1);
    } else {           // L2: rec = h2(t-1) local; in = h1(t) via LLC ring (sc1)
      const _Float16* rec = t ? h2T((t - 1) & 1) : h0fin;
      do_gemm_cat<true>(rec, rxT(t), wlds, lane, gpB, ntB, acc0, acc1);
    }
    {
      const int r0 = (lane >> 4) * 4;
      const int colb = ntB * 16 + (lane & 15);
      const int rb0 = gpB * 32;
      *(f32x4*)(gmat + (size_t)colb * GROWB + rb0 + r0)      = acc0;
      *(f32x4*)(gmat + (size_t)colb * GROWB + rb0 + 16 + r0) = acc1;
    }
    __syncthreads();
    float pre0[4], pre1[4];
#pragma unroll
    for (int q = 0; q < 4; ++q) {
      pre0[q] = gmat[(size_t)eb * GROWB + q * 16 + ec]     + biasLds[q * 16 + ec];
      pre1[q] = gmat[(size_t)eb * GROWB + q * 16 + ec + 8] + biasLds[q * 16 + ec + 8];
    }
    const float h0v = sigm(pre0[3]) * tanhf_(cst0 = sigm(pre0[1]) * cst0 +
                                             sigm(pre0[0]) * tanhf_(pre0[2]));
    const float h1v = sigm(pre1[3]) * tanhf_(cst1 = sigm(pre1[1]) * cst1 +
                                             sigm(pre1[0]) * tanhf_(pre1[2]));
    const size_t di = (size_t)eb * HD + nbase;
    const _Float16 hf0 = (_Float16)h0v, hf1 = (_Float16)h1v;
    if (!role) {
      _Float16* rl = rlT(t);
      rl[di + ec] = hf0; rl[di + ec + 8] = hf1;
      _Float16* rx = rxT(t);
      stg_sc1(rx + di + ec, hf0); stg_sc1(rx + di + ec + 8, hf1);
    } else {
      _Float16* hw = h2T(t & 1);
      hw[di + ec] = hf0; hw[di + ec + 8] = hf1;
    }
    if (fastok) __syncthreads();
    else {
      group_barrier(barA, cg, tgt, lane, wave, dead);
      if (tid == 0)
        __hip_atomic_store(role ? &cons[g] : &prod[g], (unsigned)(t + 1),
                           __ATOMIC_RELAXED, __HIP_MEMORY_SCOPE_AGENT);
    }
  }
  // role A: one extra barrier to publish prodFlag = 512 (B's t=511 gate)
  if (!role) {
    const unsigned tgt = ++barIdxA;
    if (fastok) {
      if (wave == 0) detect0(tgt, &prod[g], (unsigned)SEQ);
      else dwait(tgt);
      __syncthreads();
    } else {
      group_barrier(barA, cg, tgt, lane, wave, dead);
      if (tid == 0)
        __hip_atomic_store(&prod[g], (unsigned)SEQ, __ATOMIC_RELAXED,
                           __HIP_MEMORY_SCOPE_AGENT);
    }
  }

  // ================= pre-FC device-wide publish + FC ========================
  full_barrier();
  {
    const int j = role * 32 + cg;                 // row within 64-tile
    const _Float16* h2 = h2T((SEQ - 1) & 1) + (size_t)j * HD;
    if (tid < 384) {
      const int pc = tid >> 2, kq = tid & 3;
      const float* wrow = wfc + (size_t)pc * HD + kq * 128;
      const _Float16* hh = h2 + kq * 128;
      float a = 0.f;
#pragma unroll 8
      for (int k2 = 0; k2 < 128; ++k2) a += (float)hh[k2] * wrow[k2];
      gmatF[pc * 4 + kq] = a;
    }
    __syncthreads();
    const int brow = g * 64 + j;
    if (tid < 96) {
      const float a = gmatF[tid * 4] + gmatF[tid * 4 + 1] + gmatF[tid * 4 + 2] +
                      gmatF[tid * 4 + 3] + bfc[tid];
      out[(size_t)brow * 96 + tid] = a;
    }
    if ((dead || deadsh) && tid == 0) out[(size_t)brow * 96] = 3.0e9f;
  }
}

__global__ void ws_info_kernel(float* out, float v) { out[0] = v; }

extern "C" void kernel_launch(void* const* d_in, const int* in_sizes, int n_in,
                              void* d_out, int out_size, void* d_ws, size_t ws_size,
                              hipStream_t stream) {
  const float* x    = (const float*)d_in[0];
  const float* wih0 = (const float*)d_in[1];
  const float* whh0 = (const float*)d_in[2];
  const float* bih0 = (const float*)d_in[3];
  const float* bhh0 = (const float*)d_in[4];
  const float* wih1 = (const float*)d_in[5];
  const float* whh1 = (const float*)d_in[6];
  const float* bih1 = (const float*)d_in[7];
  const float* bhh1 = (const float*)d_in[8];
  const float* wih2 = (const float*)d_in[9];
  const float* whh2 = (const float*)d_in[10];
  const float* bih2 = (const float*)d_in[11];
  const float* bhh2 = (const float*)d_in[12];
  const float* wfc  = (const float*)d_in[13];
  const float* bfc  = (const float*)d_in[14];
  float* out = (float*)d_out;
  char* ws = (char*)d_ws;

  if (ws_size < WS_NEED) {
    hipLaunchKernelGGL(ws_info_kernel, dim3(1), dim3(1), 0, stream, out,
                       (float)(ws_size >> 20) * 1.0e6f);
    return;
  }

  hipMemsetAsync(ws, 0, 8192, stream);   // barriers + xcd table + flags

  _Float16* w0d = (_Float16*)(ws + W0_OFF);
  _Float16* w1d = (_Float16*)(ws + W1_OFF);
  _Float16* w2d = (_Float16*)(ws + W2_OFF);
  hipLaunchKernelGGL((convw<512>),  dim3(32 * 64 * 512 / 4 / 256),  dim3(256), 0, stream,
                     whh0, whh0, w0d);
  hipLaunchKernelGGL((convw<1024>), dim3(32 * 64 * 1024 / 4 / 256), dim3(256), 0, stream,
                     whh1, wih1, w1d);
  hipLaunchKernelGGL((convw<1024>), dim3(32 * 64 * 1024 / 4 / 256), dim3(256), 0, stream,
                     whh2, wih2, w2d);

  void* args[] = {(void*)&x, (void*)&wih0, (void*)&bih0, (void*)&bhh0,
                  (void*)&bih1, (void*)&bhh1, (void*)&bih2, (void*)&bhh2,
                  (void*)&wfc, (void*)&bfc, (void*)&out, (void*)&ws};
  hipError_t e = hipLaunchCooperativeKernel((const void*)lstm3_kernel,
                                            dim3(256), dim3(NTHREADS),
                                            args, 0, stream);
  if (e != hipSuccess) {
    hipLaunchKernelGGL(ws_info_kernel, dim3(1), dim3(1), 0, stream, out, 2.0e12f);
  }
}

// Round 19
// 6866.565 us; speedup vs baseline: 1.0670x; 1.0670x over previous
//
#include <hip/hip_runtime.h>
#include <stdint.h>

// ---------------------------------------------------------------------------
// 3-layer LSTM (B=256,S=512,H=512) + FC(96) -> FLOAT32 out. ROUND-19.
// Base: r17 (PASSED 7145us, best). r18's pipelined phase-B was neutral
// (interval count vs interval weight traded exactly) -- reverted.
// Single delta vs r17: LDS bank-conflict XOR-swizzles (G4/T2 recipe):
//  * weights: stage at r*KPAD + (off ^ ((r&7)<<3)) [16B-aligned bijection];
//    do_gemm2 A-reads apply the same XOR (rows r, r+16 share r&7 -> one
//    constant (lane&7)<<3 per lane).
//  * gmat: store f32x4 at colb*132 + ((row) ^ ((colb&7)<<2)) [4-word blocks
//    preserved]; epilogue reads apply the same formula.
// Measured target: SQ_LDS_BANK_CONFLICT 3.86e8 -> <1e8.
// Sentinels (float out[0]): <5e8 ws-MB*1e6 | 2e12 launch-fail | 3e9 spin-cap.
// ---------------------------------------------------------------------------

#define NGRP 8
#define BPG 32
#define HD 512
#define SEQ 512
#define TCHUNK 64
#define RSLOTS (TCHUNK + 1)
#define TILE_H (BPG * HD)
#define KPAD 1032
#define NTHREADS 512
#define GROWPAD 132

typedef _Float16 f16x8 __attribute__((ext_vector_type(8)));
typedef float f32x4 __attribute__((ext_vector_type(4)));

constexpr size_t W0_OFF   = (size_t)1 << 16;
constexpr size_t W0_SZ    = (size_t)32 * 64 * 512 * 2;
constexpr size_t W1_OFF   = W0_OFF + W0_SZ;
constexpr size_t W1_SZ    = (size_t)32 * 64 * 1024 * 2;
constexpr size_t W2_OFF   = W1_OFF + W1_SZ;
constexpr size_t H2_OFF   = W2_OFF + W1_SZ;
constexpr size_t H2_SZ    = (size_t)2 * NGRP * TILE_H * 2;
constexpr size_t RING_OFF = H2_OFF + H2_SZ;
constexpr size_t RING_SZ  = (size_t)RSLOTS * NGRP * TILE_H * 2;
constexpr size_t SEQ0_OFF = RING_OFF + RING_SZ;
constexpr size_t SEQ0_SZ  = (size_t)NGRP * SEQ * TILE_H * 2;
constexpr size_t WS_NEED  = SEQ0_OFF + SEQ0_SZ;

__device__ inline float sigm(float v) { return 1.f / (1.f + __expf(-v)); }
__device__ inline float tanhf_(float v) {
  float av = fabsf(v);
  float e = __expf(-2.f * av);
  float t = (1.f - e) / (1.f + e);
  return copysignf(t, v);
}

template <int K>
__global__ void convw(const float* __restrict__ whh, const float* __restrict__ wih,
                      _Float16* __restrict__ dst) {
  const int i = blockIdx.x * blockDim.x + threadIdx.x;
  constexpr int TOT = 32 * 64 * K / 4;
  if (i >= TOT) return;
  const int kq = i % (K / 4);
  const int rr = i / (K / 4);
  const int cg = rr >> 6, r = rr & 63;
  const int grow = (r >> 4) * 512 + cg * 16 + (r & 15);
  const int k = kq * 4;
  const float* src = (k < 512) ? (whh + (size_t)grow * 512 + k)
                               : (wih + (size_t)grow * 512 + (k - 512));
  float4 v = *(const float4*)src;
  _Float16 o[4] = {(_Float16)v.x, (_Float16)v.y, (_Float16)v.z, (_Float16)v.w};
  *(uint64_t*)(dst + (size_t)i * 4) = *(const uint64_t*)o;
}

// ---- stage weights into LDS with row-XOR swizzle (bits 3..5 of half-off) ---
template <int K>
__device__ inline void stage_w(const _Float16* __restrict__ src,
                               _Float16* __restrict__ wlds, int tid) {
  constexpr int C = 64 * K / 8;
#pragma unroll 4
  for (int ci = tid; ci < C; ci += NTHREADS) {
    const int r = ci / (K / 8);
    const int kc = (ci % (K / 8)) * 8;
    *(f16x8*)(wlds + (size_t)r * KPAD + (kc ^ ((r & 7) << 3))) =
        *(const f16x8*)(src + (size_t)r * K + kc);
  }
}

// ---- wave's GEMM share: ONE B-slice, TWO A row-tiles; swizzled A-reads -----
template <int NS>
__device__ inline void do_gemm2(const _Float16* __restrict__ bbase,
                                const _Float16* __restrict__ wlds,
                                int aKoff, int bKoff, int lane, int gp, int nt,
                                f32x4& acc0, f32x4& acc1) {
  const int bcol = nt * 16 + (lane & 15);
  const int krow = (lane >> 4) * 8;
  const int ax = (lane & 7) << 3;          // rows r and r+16 share (r&7)
  const _Float16* arow0 = wlds + (size_t)(gp * 32 + (lane & 15)) * KPAD;
  const _Float16* arow1 = arow0 + (size_t)16 * KPAD;
  const _Float16* brow  = bbase + (size_t)bcol * HD + bKoff + krow;
  constexpr int CH = (NS > 8) ? 8 : NS;
#pragma unroll
  for (int base = 0; base < NS; base += CH) {
    f16x8 br[CH];
#pragma unroll
    for (int s = 0; s < CH; ++s) br[s] = *(const f16x8*)(brow + (base + s) * 32);
#pragma unroll
    for (int s = 0; s < CH; ++s) {
      const int aoff = (aKoff + krow + (base + s) * 32) ^ ax;
      f16x8 a0 = *(const f16x8*)(arow0 + aoff);
      acc0 = __builtin_amdgcn_mfma_f32_16x16x32_f16(a0, br[s], acc0, 0, 0, 0);
      f16x8 a1 = *(const f16x8*)(arow1 + aoff);
      acc1 = __builtin_amdgcn_mfma_f32_16x16x32_f16(a1, br[s], acc1, 0, 0, 0);
    }
  }
}

// ---- full barrier (agent fences) [verified rounds 2/3/13] ------------------
__device__ inline void group_barrier(unsigned* slots, int cg, unsigned target,
                                     int lane, int wave, bool& dead) {
  __syncthreads();
  if (wave == 0) {
    if (lane == 0) {
      __builtin_amdgcn_fence(__ATOMIC_RELEASE, "agent");
      __hip_atomic_store(&slots[cg], target, __ATOMIC_RELAXED, __HIP_MEMORY_SCOPE_AGENT);
    }
    if (!dead) {
      unsigned* myslot = &slots[lane & 31];
      int spins = 0;
      while (true) {
        unsigned v = __hip_atomic_load(myslot, __ATOMIC_RELAXED, __HIP_MEMORY_SCOPE_AGENT);
        if (__all((int)(v >= target))) break;
        __builtin_amdgcn_s_sleep(1);
        if (++spins > (1 << 22)) { dead = true; break; }
      }
    }
    if (lane == 0) __builtin_amdgcn_fence(__ATOMIC_ACQUIRE, "agent");
  }
  __syncthreads();
}

__global__ __launch_bounds__(NTHREADS, 2) void lstm3_kernel(
    const float* __restrict__ x,
    const float* __restrict__ wih0,
    const float* __restrict__ bih0, const float* __restrict__ bhh0,
    const float* __restrict__ bih1, const float* __restrict__ bhh1,
    const float* __restrict__ bih2, const float* __restrict__ bhh2,
    const float* __restrict__ wfc, const float* __restrict__ bfc,
    float* __restrict__ out, char* __restrict__ ws) {
  __shared__ __align__(16) char smem[149504];
  __shared__ unsigned door;
  _Float16* wlds = (_Float16*)smem;                 // [64][KPAD] fp16 (swizzled)
  float* biasLds = (float*)(smem + 132096);         // [64]
  float* w0Lds   = (float*)(smem + 132352);         // [64]
  float* gmat    = (float*)(smem + 132608);         // [32 batch][GROWPAD] swz
  float* gmatF   = (float*)(smem + 132608);

  const int bid = blockIdx.x;
  const int grp = bid & 7;
  const int cg  = bid >> 3;
  const int tid = threadIdx.x;
  const int lane = tid & 63;
  const int wave = tid >> 6;
  const int gp = wave & 1;
  const int nt = (wave >> 1) & 1;
  const int kh = wave >> 2;
  const int nbase = cg * 16;
  const int ab = tid >> 4;
  const int an = tid & 15;

  unsigned* barA = (unsigned*)ws + grp * 64;                 // LLC flags
  unsigned* barB = (unsigned*)(ws + 4096) + grp * 64;        // L2 flags
  const _Float16* wcv0 = (const _Float16*)(ws + W0_OFF) + (size_t)cg * 64 * 512;
  const _Float16* wcv1 = (const _Float16*)(ws + W1_OFF) + (size_t)cg * 64 * 1024;
  const _Float16* wcv2 = (const _Float16*)(ws + W2_OFF) + (size_t)cg * 64 * 1024;
  _Float16* h2b  = (_Float16*)(ws + H2_OFF);
  _Float16* ring = (_Float16*)(ws + RING_OFF);
  _Float16* seq0 = (_Float16*)(ws + SEQ0_OFF);

  unsigned barIdxA = 0;
  bool dead = false;
  if (tid == 0) door = 0;

  // ---- startup: XCD detect -------------------------------------------------
  int myxcc = 0;
  asm volatile("s_getreg_b32 %0, hwreg(HW_REG_XCC_ID)" : "=s"(myxcc));
  int* xcds = (int*)(ws + 2048);
  if (tid == 0) xcds[bid] = myxcc;
  group_barrier(barA, cg, ++barIdxA, lane, wave, dead);
  bool local = true, allsame = true;
  for (int j = 0; j < BPG; ++j) local = local && (xcds[grp + 8 * j] == myxcc);
  for (int j = 0; j < NGRP * BPG; ++j) allsame = allsame && (xcds[j] == myxcc);
  if (allsame) local = false;
  const bool fastok = local;

  auto seqTile  = [&](int t) { return seq0 + ((size_t)(grp * SEQ + t)) * TILE_H; };
  auto ringTile = [&](int t) { return ring + ((size_t)(t % RSLOTS) * NGRP + grp) * TILE_H; };
  auto h2Tile   = [&](int s) { return h2b + ((size_t)s * NGRP + grp) * TILE_H; };

  auto step = [&](const _Float16* recB, const _Float16* inB, float xv, float& cst,
                  _Float16* houtTile, bool skip,
                  const char* pf1, const char* pf2) {
    float pfacc = 0.f;
    if (pf1 != nullptr && tid < 128) {
      float4 v = ((const float4*)pf1)[tid];
      pfacc += v.x + v.y + v.z + v.w;
    }
    if (pf2 != nullptr && tid >= 128 && tid < 256) {
      float4 v = ((const float4*)pf2)[tid - 128];
      pfacc += v.x + v.y + v.z + v.w;
    }
    const bool phaseB = (inB != nullptr);
    const unsigned tgt = ++barIdxA;
    if (fastok) {
      if (wave == 0) {
        if (lane == 0) {
          *(volatile unsigned*)&barB[cg] = tgt;    // plain -> shared XCD L2
          __hip_atomic_store(&barA[cg], tgt, __ATOMIC_RELAXED, __HIP_MEMORY_SCOPE_AGENT);
        }
        if (!dead) {
          bool ok = false;
          const volatile unsigned* fs = &barB[lane & 31];
          for (int it = 0; it < 64 && !ok; ++it) {
            asm volatile("buffer_inv\ns_waitcnt vmcnt(0)" ::: "memory");
            unsigned v = *fs;
            ok = __all((int)(v >= tgt));
          }
          if (!ok) {
            unsigned* ss = &barA[lane & 31];
            int s2 = 0;
            while (true) {
              unsigned v = __hip_atomic_load(ss, __ATOMIC_RELAXED,
                                             __HIP_MEMORY_SCOPE_AGENT);
              if (__all((int)(v >= tgt))) break;
              __builtin_amdgcn_s_sleep(1);
              if (++s2 > (1 << 22)) { dead = true; break; }
            }
            asm volatile("buffer_inv\ns_waitcnt vmcnt(0)" ::: "memory");
          }
        }
        if (lane == 0)
          __hip_atomic_store(&door, tgt, __ATOMIC_RELEASE, __HIP_MEMORY_SCOPE_WORKGROUP);
      } else if (wave < 4 || !phaseB) {
        while (__hip_atomic_load(&door, __ATOMIC_ACQUIRE, __HIP_MEMORY_SCOPE_WORKGROUP)
               < tgt) {}
      }
    }
    f32x4 acc0 = {0.f, 0.f, 0.f, 0.f};
    f32x4 acc1 = {0.f, 0.f, 0.f, 0.f};
    if (!skip) {
      if (!phaseB) {
        do_gemm2<8>(recB, wlds, kh * 256, kh * 256, lane, gp, nt, acc0, acc1);
      } else {
        const _Float16* bb = kh ? inB : recB;
        do_gemm2<16>(bb, wlds, kh * 512, 0, lane, gp, nt, acc0, acc1);
      }
    }
    {
      // gmat swizzled: word = colb*GROWPAD + (row ^ ((colb&7)<<2))
      const int r0 = (lane >> 4) * 4;
      const int colb = nt * 16 + (lane & 15);
      const int rb0 = kh * 64 + gp * 32;
      const int gx = (colb & 7) << 2;
      *(f32x4*)(gmat + (size_t)colb * GROWPAD + ((rb0 + r0) ^ gx))      = acc0;
      *(f32x4*)(gmat + (size_t)colb * GROWPAD + ((rb0 + 16 + r0) ^ gx)) = acc1;
    }
    asm volatile("" :: "v"(pfacc));
    __syncthreads();                       // (B) gmat ready
    const int gx2 = (ab & 7) << 2;
    float pre[4];
#pragma unroll
    for (int g = 0; g < 4; ++g) {
      float s = gmat[(size_t)ab * GROWPAD + ((g * 16 + an) ^ gx2)] +
                gmat[(size_t)ab * GROWPAD + ((64 + g * 16 + an) ^ gx2)];
      pre[g] = s + biasLds[g * 16 + an] + xv * w0Lds[g * 16 + an];
    }
    const float gi = sigm(pre[0]);
    const float gf = sigm(pre[1]);
    const float gg = tanhf_(pre[2]);
    const float go = sigm(pre[3]);
    cst = gf * cst + gi * gg;
    const float h = go * tanhf_(cst);
    houtTile[(size_t)ab * HD + nbase + an] = (_Float16)h;
    if (fastok) __syncthreads();           // (A) drains h to shared L2
    else group_barrier(barA, cg, tgt, lane, wave, dead);
  };

  // ---------------- phase A: layer 0 (K=512, input is scalar x) -------------
  stage_w<512>(wcv0, wlds, tid);
  if (tid < 64) {
    const int grow2 = (tid >> 4) * 512 + nbase + (tid & 15);
    biasLds[tid] = bih0[grow2] + bhh0[grow2];
    w0Lds[tid] = wih0[grow2];
  }
  __syncthreads();

  float c0 = 0.f;
  for (int t = 0; t < SEQ; ++t) {
    const _Float16* recB = t ? seqTile(t - 1) : seq0;
    const float xv = x[(size_t)(grp * 32 + ab) * SEQ + t];
    const char* pf1 = nullptr;
    if (t >= 384 && t < 448)  pf1 = (const char*)wcv1 + (size_t)(t - 384) * 2048;
    else if (t >= 448)        pf1 = (const char*)seqTile(t - 448) + (size_t)cg * 2048;
    step(recB, nullptr, xv, c0, seqTile(t), t == 0, pf1, nullptr);
  }
  const float c0sav = c0;
  const _Float16* h0tile = seqTile(SEQ - 1);

  // ---------------- phase B: layers 1+2 interleaved in chunks ---------------
  float c1 = c0sav, c2 = c0sav;
  for (int ch = 0; ch < SEQ / TCHUNK; ++ch) {
    // L1 sub-phase
    __syncthreads();
    stage_w<1024>(wcv1, wlds, tid);
    if (tid < 64) {
      const int grow2 = (tid >> 4) * 512 + nbase + (tid & 15);
      biasLds[tid] = bih1[grow2] + bhh1[grow2];
      w0Lds[tid] = 0.f;
    }
    __syncthreads();
    for (int tt = 0; tt < TCHUNK; ++tt) {
      const int t = ch * TCHUNK + tt;
      const _Float16* recB = t ? ringTile(t - 1) : h0tile;
      const char* pf1 = (const char*)wcv2 + (size_t)tt * 2048;
      step(recB, seqTile(t), 0.f, c1, ringTile(t), false, pf1, nullptr);
    }
    // L2 sub-phase
    __syncthreads();
    stage_w<1024>(wcv2, wlds, tid);
    if (tid < 64) {
      const int grow2 = (tid >> 4) * 512 + nbase + (tid & 15);
      biasLds[tid] = bih2[grow2] + bhh2[grow2];
      w0Lds[tid] = 0.f;
    }
    __syncthreads();
    const bool more = (ch + 1) < SEQ / TCHUNK;
    for (int tt = 0; tt < TCHUNK; ++tt) {
      const int t = ch * TCHUNK + tt;
      const _Float16* recB = t ? h2Tile((t - 1) & 1) : h0tile;
      const char* pf1 = more ? (const char*)seqTile((ch + 1) * TCHUNK + tt) +
                               (size_t)cg * 2048 : nullptr;
      const char* pf2 = more ? (const char*)wcv1 + (size_t)tt * 2048 : nullptr;
      step(recB, ringTile(t), 0.f, c2, h2Tile(t & 1), false, pf1, pf2);
    }
  }

  // final cross-block publish before FC (h2 read across blocks)
  group_barrier(barA, cg, ++barIdxA, lane, wave, dead);

  // ---------------- final FC: out[b,:] = h2[b,:] @ Wfc^T + bfc (FLOAT32) ----
  {
    const _Float16* h2 = h2Tile((SEQ - 1) & 1) + (size_t)cg * HD;
    if (tid < 384) {
      const int pc = tid >> 2, kq = tid & 3;
      const float* wrow = wfc + (size_t)pc * HD + kq * 128;
      const _Float16* hh = h2 + kq * 128;
      float a = 0.f;
#pragma unroll 8
      for (int k2 = 0; k2 < 128; ++k2) a += (float)hh[k2] * wrow[k2];
      gmatF[pc * 4 + kq] = a;
    }
    __syncthreads();
    if (tid < 96) {
      const float a = gmatF[tid * 4] + gmatF[tid * 4 + 1] + gmatF[tid * 4 + 2] +
                      gmatF[tid * 4 + 3] + bfc[tid];
      out[(size_t)(grp * 32 + cg) * 96 + tid] = a;
    }
    if (dead && tid == 0)
      out[(size_t)(grp * 32 + cg) * 96] = 3.0e9f;
  }
}

__global__ void ws_info_kernel(float* out, float v) { out[0] = v; }

extern "C" void kernel_launch(void* const* d_in, const int* in_sizes, int n_in,
                              void* d_out, int out_size, void* d_ws, size_t ws_size,
                              hipStream_t stream) {
  const float* x    = (const float*)d_in[0];
  const float* wih0 = (const float*)d_in[1];
  const float* whh0 = (const float*)d_in[2];
  const float* bih0 = (const float*)d_in[3];
  const float* bhh0 = (const float*)d_in[4];
  const float* wih1 = (const float*)d_in[5];
  const float* whh1 = (const float*)d_in[6];
  const float* bih1 = (const float*)d_in[7];
  const float* bhh1 = (const float*)d_in[8];
  const float* wih2 = (const float*)d_in[9];
  const float* whh2 = (const float*)d_in[10];
  const float* bih2 = (const float*)d_in[11];
  const float* bhh2 = (const float*)d_in[12];
  const float* wfc  = (const float*)d_in[13];
  const float* bfc  = (const float*)d_in[14];
  float* out = (float*)d_out;
  char* ws = (char*)d_ws;

  if (ws_size < WS_NEED) {
    hipLaunchKernelGGL(ws_info_kernel, dim3(1), dim3(1), 0, stream, out,
                       (float)(ws_size >> 20) * 1.0e6f);
    return;
  }

  hipMemsetAsync(ws, 0, 8192, stream);   // barA + xcd table + barB

  _Float16* w0d = (_Float16*)(ws + W0_OFF);
  _Float16* w1d = (_Float16*)(ws + W1_OFF);
  _Float16* w2d = (_Float16*)(ws + W2_OFF);
  hipLaunchKernelGGL((convw<512>),  dim3(32 * 64 * 512 / 4 / 256),  dim3(256), 0, stream,
                     whh0, whh0, w0d);
  hipLaunchKernelGGL((convw<1024>), dim3(32 * 64 * 1024 / 4 / 256), dim3(256), 0, stream,
                     whh1, wih1, w1d);
  hipLaunchKernelGGL((convw<1024>), dim3(32 * 64 * 1024 / 4 / 256), dim3(256), 0, stream,
                     whh2, wih2, w2d);

  void* args[] = {(void*)&x, (void*)&wih0, (void*)&bih0, (void*)&bhh0,
                  (void*)&bih1, (void*)&bhh1, (void*)&bih2, (void*)&bhh2,
                  (void*)&wfc, (void*)&bfc, (void*)&out, (void*)&ws};
  hipError_t e = hipLaunchCooperativeKernel((const void*)lstm3_kernel,
                                            dim3(NGRP * BPG), dim3(NTHREADS),
                                            args, 0, stream);
  if (e != hipSuccess) {
    hipLaunchKernelGGL(ws_info_kernel, dim3(1), dim3(1), 0, stream, out, 2.0e12f);
  }
}